// Round 3
// 177.996 us; speedup vs baseline: 1.0279x; 1.0279x over previous
//
#include <hip/hip_runtime.h>
#include <math.h>

#define NT    300
#define NA    3
#define BATCH 16
#define NCLS  80
#define CCH   85
#define NBO   394             // obj blocks: 300 (L0) + 75 (L1) + 19 (L2)
#define NBT   675             // target blocks: 4 waves/block, one ROW per WAVE
#define NBLK  (NBO + NBT)

// ws layout (byte offsets) — every slot written unconditionally by main_kernel,
// so NO pre-zeroing (and no memset dispatch) is needed; harness may poison ws:
//   0     : double obj_part[394]      per-obj-block softplus partial
//   3200  : double tgt_part[675][4]   per-target-block {lbox, lcls, nval, objcorr}
// total 24800 B. No row arrays, no hash table: the last-wins winner of a
// scatter cell is a pure function of targets+anchors, so each target wave
// decides winner-ship locally by scanning later targets of the same anchor.

__device__ __forceinline__ float softplusf(float x) {
    // == max(x,0) + log1p(exp(-|x|)) == bce(x, 0)
    return fmaxf(x, 0.f) + log1pf(expf(-fabsf(x)));
}

// 256-thread block reduce; result valid on thread 0. Safe for repeated calls
// (trailing barrier prevents WAR on red[]).
__device__ __forceinline__ double block_reduce(double v, double* red) {
    #pragma unroll
    for (int off = 32; off > 0; off >>= 1) v += __shfl_down(v, off, 64);
    const int wid = threadIdx.x >> 6, lane = threadIdx.x & 63;
    if (lane == 0) red[wid] = v;
    __syncthreads();
    double r = (threadIdx.x < 4) ? red[threadIdx.x] : 0.0;
    r += __shfl_down(r, 2, 64);
    r += __shfl_down(r, 1, 64);
    __syncthreads();
    return r;
}

__global__ __launch_bounds__(256) void main_kernel(
    const float* __restrict__ p0, const float* __restrict__ p1,
    const float* __restrict__ p2,
    const float* __restrict__ targets, const float* __restrict__ anchors,
    char* __restrict__ ws)
{
    __shared__ double red[4];
    __shared__ double acc[4][4];   // [wave][quantity: lb, lc, nv, co]

    double* obj_part = (double*)ws;
    double* tgt_part = (double*)(ws + 3200);

    if (blockIdx.x < NBO) {
        // ---------- obj softplus sweep: 4 independent gathers/thread --------
        const int ob = blockIdx.x;
        int li, bb;
        if (ob < 300)      { li = 0; bb = ob; }
        else if (ob < 375) { li = 1; bb = ob - 300; }
        else               { li = 2; bb = ob - 375; }
        const float* p = (li == 0) ? p0 : ((li == 1) ? p1 : p2);
        const int N = (BATCH * NA * 6400) >> (2*li);   // 307200/76800/19200

        float s = 0.f;
        #pragma unroll
        for (int k = 0; k < 4; ++k) {
            const int idx = bb * 1024 + k * 256 + threadIdx.x;
            if (idx < N) s += softplusf(p[(size_t)idx * CCH + 4]);
        }
        const double t = block_reduce((double)s, red);
        if (threadIdx.x == 0) obj_part[ob] = t;
        return;
    }

    // ---------- per-target math: ONE ROW PER WAVE ---------------------------
    const int tb   = blockIdx.x - NBO;
    const int gr   = tb * 4 + (threadIdx.x >> 6);         // global row
    const int lane = threadIdx.x & 63;
    const int li   = gr / (NA * NT);
    const int r    = gr - li * (NA * NT);                 // a*NT + ti
    const int a    = r / NT;
    const int ti   = r - a * NT;
    const float* p = (li == 0) ? p0 : ((li == 1) ? p1 : p2);
    const int W = 80 >> li, H = W;

    // wave-uniform scalars (broadcast loads)
    const float img = targets[ti*6 + 0];
    const float cls = targets[ti*6 + 1];
    const float tx  = targets[ti*6 + 2] * (float)W;
    const float ty  = targets[ti*6 + 3] * (float)H;
    const float tw  = targets[ti*6 + 4] * (float)W;
    const float th  = targets[ti*6 + 5] * (float)H;

    const float ax = anchors[(li*3 + a)*2 + 0];
    const float ay = anchors[(li*3 + a)*2 + 1];
    const float rx = tw / ax, ry = th / ay;
    const float mr = fmaxf(fmaxf(rx, 1.f/rx), fmaxf(ry, 1.f/ry));
    const bool  mask = mr < 4.f;
    const float mf = mask ? 1.f : 0.f;

    const int b = (int)img;
    const int c = (int)cls;
    const int gij_x = (int)tx;          // trunc == floor (positive)
    const int gij_y = (int)ty;
    const int gi = min(max(gij_x, 0), W - 1);
    const int gj = min(max(gij_y, 0), H - 1);

    // last-wins dedup, recomputed locally: row i loses iff some later target
    // tj (same layer, same anchor, same image) is masked-in and lands in the
    // same integer cell. targets is 7.2 KB -> L1-resident; ~5 iters/lane.
    bool beaten = false;
    for (int tj = ti + 1 + lane; tj < NT; tj += 64) {
        const float img_j = targets[tj*6 + 0];
        const float xj = targets[tj*6 + 2] * (float)W;
        const float yj = targets[tj*6 + 3] * (float)H;
        const float wj = targets[tj*6 + 4] * (float)W;
        const float hj = targets[tj*6 + 5] * (float)H;
        const float rxj = wj / ax, ryj = hj / ay;
        const float mrj = fmaxf(fmaxf(rxj, 1.f/rxj), fmaxf(ryj, 1.f/ryj));
        if (mrj < 4.f && img_j == img) {
            const int gi_j = min(max((int)xj, 0), W - 1);
            const int gj_j = min(max((int)yj, 0), H - 1);
            if (gi_j == gi && gj_j == gj) beaten = true;
        }
    }
    const bool winner = mask && !__any(beaten);

    // reference quirk: anch = anchors[a, a] (layer-independent)
    const float anch_x = anchors[(a*3 + a)*2 + 0];
    const float anch_y = anchors[(a*3 + a)*2 + 1];

    const int match = BATCH - 1 - b;
    const int cell  = ((match*NA + a)*H + gj)*W + gi;
    const float* ps = p + (size_t)cell * CCH;

    // coalesced: 2 wave-load instructions cover all 85 channels
    const float x1 = ps[lane];                                // ch 0..63
    const float x2 = (lane < CCH - 64) ? ps[64 + lane] : 0.f; // ch 64..84

    const float s0   = __shfl(x1, 0);
    const float s1   = __shfl(x1, 1);
    const float s2   = __shfl(x1, 2);
    const float s3   = __shfl(x1, 3);
    const float objx = __shfl(x1, 4);

    // cls: sum_k softplus(ps[5+k]) - ps[5+c]
    const int ch = 5 + c;
    float contrib = (lane >= 5) ? softplusf(x1) : 0.f;
    if (lane < CCH - 64) contrib += softplusf(x2);
    if (lane == ch) contrib -= x1;
    if (ch >= 64 && lane == ch - 64) contrib -= x2;
    #pragma unroll
    for (int off = 32; off > 0; off >>= 1)
        contrib += __shfl_down(contrib, off, 64);             // lane 0 has sum

    // box math (wave-uniform)
    const float pxx = 1.f / (1.f + expf(-s0));
    const float pyy = 1.f / (1.f + expf(-s1));
    const float pw  = expf(s2) * anch_x;
    const float ph  = expf(s3) * anch_y;
    const float fx  = tx - (float)gij_x;
    const float fy  = ty - (float)gij_y;

    const float eps = 1e-9f;
    const float b1x1 = pxx - pw*0.5f, b1x2 = pxx + pw*0.5f;
    const float b1y1 = pyy - ph*0.5f, b1y2 = pyy + ph*0.5f;
    const float b2x1 = fx - tw*0.5f,  b2x2 = fx + tw*0.5f;
    const float b2y1 = fy - th*0.5f,  b2y2 = fy + th*0.5f;
    float iw = fminf(b1x2, b2x2) - fmaxf(b1x1, b2x1); iw = fmaxf(iw, 0.f);
    float ih = fminf(b1y2, b2y2) - fmaxf(b1y1, b2y1); ih = fmaxf(ih, 0.f);
    const float inter = iw * ih;
    const float w1 = b1x2 - b1x1, h1 = b1y2 - b1y1 + eps;
    const float w2 = b2x2 - b2x1, h2 = b2y2 - b2y1 + eps;
    const float uni = w1*h1 + w2*h2 - inter + eps;
    const float iou = inter / uni;
    const float cw  = fmaxf(b1x2, b2x2) - fminf(b1x1, b2x1);
    const float chh = fmaxf(b1y2, b2y2) - fminf(b1y1, b2y1);
    const float c2 = cw*cw + chh*chh + eps;
    const float dx = b2x1 + b2x2 - b1x1 - b1x2;
    const float dy = b2y1 + b2y2 - b1y1 - b1y2;
    const float rho2 = (dx*dx + dy*dy) * 0.25f;
    const float dat = atanf(w2/h2) - atanf(w1/h1);
    const float v = 0.40528473456935108577f * dat * dat;      // 4/pi^2
    const float alpha = v / (1.f + eps - iou + v);
    const float ciou = iou - (rho2/c2 + v*alpha);

    if (lane == 0) {
        const int wid = threadIdx.x >> 6;
        acc[wid][0] = (double)((1.f - ciou) * mf);
        acc[wid][1] = (double)(contrib * mf);
        acc[wid][2] = (double)mf;
        acc[wid][3] = winner ? (double)(objx * fmaxf(ciou, 0.f)) : 0.0;
    }
    __syncthreads();
    // unconditional write of this block's 4 partials (poison-proof)
    if (threadIdx.x < 4) {
        tgt_part[tb*4 + threadIdx.x] =
            acc[0][threadIdx.x] + acc[1][threadIdx.x] +
            acc[2][threadIdx.x] + acc[3][threadIdx.x];
    }
}

__global__ __launch_bounds__(256) void final_kernel(
    const char* __restrict__ ws, float* __restrict__ out)
{
    __shared__ double red[4];
    const double* obj_part = (const double*)ws;
    const double* tgt_part = (const double*)(ws + 3200);

    double so[3] = {0,0,0};
    double lb[3] = {0,0,0}, lc[3] = {0,0,0}, nv[3] = {0,0,0}, co[3] = {0,0,0};

    for (int bk = threadIdx.x; bk < NBO; bk += 256) {
        const int l = (bk < 300) ? 0 : ((bk < 375) ? 1 : 2);
        so[l] += obj_part[bk];
    }
    // target blocks: tb<225 -> L0, tb<450 -> L1, else L2 (4 rows/block, same layer)
    for (int tb = threadIdx.x; tb < NBT; tb += 256) {
        const int l = (tb < 225) ? 0 : ((tb < 450) ? 1 : 2);
        lb[l] += tgt_part[tb*4 + 0];
        lc[l] += tgt_part[tb*4 + 1];
        nv[l] += tgt_part[tb*4 + 2];
        co[l] += tgt_part[tb*4 + 3];
    }

    double rsum[15];
    #pragma unroll
    for (int l = 0; l < 3; ++l) {
        rsum[l*5 + 0] = block_reduce(lb[l], red);
        rsum[l*5 + 1] = block_reduce(lc[l], red);
        rsum[l*5 + 2] = block_reduce(co[l], red);
        rsum[l*5 + 3] = block_reduce(nv[l], red);
        rsum[l*5 + 4] = block_reduce(so[l], red);
    }

    if (threadIdx.x == 0) {
        double lbox = 0.0, lobj = 0.0, lcls = 0.0;
        for (int l = 0; l < 3; ++l) {
            const double nvv = fmax(rsum[l*5 + 3], 1.0);
            lbox += rsum[l*5 + 0] / nvv;
            lcls += rsum[l*5 + 1] / (nvv * (double)NCLS);
            const double N = (double)((BATCH * NA * 6400) >> (2*l));
            lobj += (rsum[l*5 + 4] - rsum[l*5 + 2]) / N;
        }
        lbox *= 0.05;
        lcls *= 0.5;
        const double loss = lbox + lobj + lcls;
        out[0] = (float)loss;
        out[1] = (float)lbox;
        out[2] = (float)lobj;
        out[3] = (float)lcls;
        out[4] = (float)loss;
    }
}

extern "C" void kernel_launch(void* const* d_in, const int* in_sizes, int n_in,
                              void* d_out, int out_size, void* d_ws, size_t ws_size,
                              hipStream_t stream) {
    const float* p0      = (const float*)d_in[0];
    const float* p1      = (const float*)d_in[1];
    const float* p2      = (const float*)d_in[2];
    const float* targets = (const float*)d_in[3];
    const float* anchors = (const float*)d_in[4];

    main_kernel<<<NBLK, 256, 0, stream>>>(p0, p1, p2, targets, anchors,
                                          (char*)d_ws);
    final_kernel<<<1, 256, 0, stream>>>((const char*)d_ws, (float*)d_out);
}